// Round 1
// 301.379 us; speedup vs baseline: 1.0104x; 1.0104x over previous
//
#include <hip/hip_runtime.h>
#include <cmath>

#define XR_BB   16   // b-rows per block in xred kernel
#define OGROUP  8    // o-rows per block in main kernel
#define BCHUNK  16   // b-values per block in main kernel

// ---------------- Kernel 1: x_red[b,r] = sum_i x[b,i] * mask[r,i] ----------------
// Full mask staged in LDS (padded rows, conflict-free), x staged transposed so the
// inner loop is broadcast ds_read_b128.
__global__ __launch_bounds__(256) void xred_kernel(const float* __restrict__ x,
                                                   const float* __restrict__ mask,
                                                   float* __restrict__ xred) {
    __shared__ float ms[128][129];   // +1 pad: compute-read bank = (r+i)&31 -> 2-way = free
    __shared__ float xs[128][20];    // transposed [i][b], pad 20 keeps 16B align for float4
    const int tid   = threadIdx.x;
    const int bbase = blockIdx.x * XR_BB;

    // stage mask: 16384 floats via float4 global loads (coalesced)
    const float4* m4 = (const float4*)mask;
    for (int k = tid; k < 4096; k += 256) {
        float4 v = m4[k];
        int row = k >> 5;            // 32 float4 per 128-wide row
        int col = (k & 31) * 4;
        ms[row][col]     = v.x;
        ms[row][col + 1] = v.y;
        ms[row][col + 2] = v.z;
        ms[row][col + 3] = v.w;
    }
    // stage x transposed
    for (int k = tid; k < XR_BB * 128; k += 256) {
        int b = k >> 7, i = k & 127;
        xs[i][b] = x[(size_t)(bbase + b) * 128 + i];
    }
    __syncthreads();

    const int r = tid & 127;
    const int g = tid >> 7;          // 0/1 -> b offset 8g
    float acc[8] = {0.f, 0.f, 0.f, 0.f, 0.f, 0.f, 0.f, 0.f};
    for (int i = 0; i < 128; ++i) {
        const float  m  = ms[r][i];                          // 2-way alias, free
        const float4 xa = *(const float4*)&xs[i][8 * g];     // broadcast b128
        const float4 xb = *(const float4*)&xs[i][8 * g + 4]; // broadcast b128
        acc[0] += m * xa.x; acc[1] += m * xa.y; acc[2] += m * xa.z; acc[3] += m * xa.w;
        acc[4] += m * xb.x; acc[5] += m * xb.y; acc[6] += m * xb.z; acc[7] += m * xb.w;
    }
    #pragma unroll
    for (int j = 0; j < 8; ++j)
        xred[(size_t)(bbase + 8 * g + j) * 128 + r] = acc[j];
}

// ---------------- Kernel 2: z, postacts, y ----------------
// Restructured for write locality: thread owns an i-quad of ONE o-row (4 elements,
// float4 store). Block = 256 threads = 8 consecutive o-rows; per b it writes a 4 KB
// contiguous span, and consecutive blockIdx.x fill a full 64 KB postacts[b] row.
// fun_id-dependent masks/coefs hoisted into registers, reused over BCHUNK b-values.
__global__ __launch_bounds__(256, 4) void kan_main(const float4* __restrict__ xred4,
                                                   const float4* __restrict__ affine,
                                                   const int* __restrict__ fun_ids,
                                                   float* __restrict__ y,
                                                   float4* __restrict__ post4) {
    const int tid = threadIdx.x;
    const int oo  = tid >> 5;                 // 0..7 : o-row within block
    const int il  = tid & 31;                 // i-quad index (i = 4*il .. 4*il+3)
    const int o   = blockIdx.x * OGROUP + oo;

    // ---- hoist per-element affine + fun_id-derived state (b-invariant) ----
    float4 A[4]; int f[4];
    #pragma unroll
    for (int j = 0; j < 4; ++j) {
        A[j] = affine[(size_t)o * 128 + il * 4 + j];
        f[j] = fun_ids[(size_t)o * 128 + il * 4 + j];
    }

    bool m1[4], m2[4], m3[4], m7[4], m8[4], me[4];
    float k1[4], k2[4], An[4], Bn[4], Dd[4];
    #pragma unroll
    for (int j = 0; j < 4; ++j) {
        const int fj = f[j];
        m1[j] = (fj == 1); m2[j] = (fj == 2); m3[j] = (fj == 3);
        m7[j] = (fj == 7); m8[j] = (fj == 8);
        me[j] = (fj >= 4 && fj <= 6) || (fj == 9);
        // exp-group: arg = k1*z + k2*z^2 ; r = (An + Bn*e)/(1 + Dd*e)
        float k1v = 0.f, k2v = 0.f, Anv = 0.f, Bnv = 1.f, Ddv = 0.f;
        if      (fj == 4) { k1v = -2.f; Anv = 1.f; Bnv = -1.f; Ddv = 1.f; }  // tanh
        else if (fj == 5) { k1v = -1.f; Anv = 1.f; Bnv =  0.f; Ddv = 1.f; }  // sigmoid
        else if (fj == 6) { k2v = -1.f; }                                    // exp(-z^2)
        else if (fj == 9) { k1v =  1.f; }                                    // exp(z)
        k1[j] = k1v; k2[j] = k2v; An[j] = Anv; Bn[j] = Bnv; Dd[j] = Ddv;
    }

    const int b0 = blockIdx.y * BCHUNK;

    for (int bb = 0; bb < BCHUNK; ++bb) {
        const int b = b0 + bb;
        // both half-waves read the same 512 B row slice -> L1/L2 broadcast
        const float4 xr = xred4[(size_t)b * 32 + il];
        const float xv[4] = {xr.x, xr.y, xr.z, xr.w};

        float p[4];
        #pragma unroll
        for (int j = 0; j < 4; ++j) {
            const float z  = fmaf(A[j].x, xv[j], A[j].y);
            const float zz = z * z;
            float pv = m1[j] ? zz : z;
            pv = m2[j] ? zz * z : pv;
            pv = m7[j] ? fabsf(z) : pv;
            const float s = __sinf(z);
            pv = m3[j] ? s : pv;
            const float arg = fminf(fmaf(k2[j], zz, k1[j] * z), 80.f);
            const float e   = __expf(arg);
            const float num = fmaf(Bn[j], e, An[j]);
            const float den = fmaf(Dd[j], e, 1.0f);
            const float r   = num * __builtin_amdgcn_rcpf(den);
            pv = me[j] ? r : pv;
            const float az  = fabsf(z);
            const bool  big = az > 1.0f;
            const float t   = big ? __builtin_amdgcn_rcpf(az) : az;
            const float t2  = t * t;
            float q = fmaf(t2, -0.01172120f, 0.05265332f);
            q = fmaf(t2, q, -0.11643287f);
            q = fmaf(t2, q,  0.19354346f);
            q = fmaf(t2, q, -0.33262347f);
            q = fmaf(t2, q,  0.99997726f);
            q = t * q;
            q = big ? 1.57079632679f - q : q;
            const float at = copysignf(q, z);
            pv = m8[j] ? at : pv;
            p[j] = fmaf(A[j].z, pv, A[j].w);
        }

        // wave stores 1 KB contiguous (2 o-rows); block stores 4 KB contiguous per b
        post4[((size_t)b * 128 + o) * 32 + il] = make_float4(p[0], p[1], p[2], p[3]);

        // y[b,o] = sum_i postacts : xor-tree over the 32 lanes of this o-row
        float s = (p[0] + p[1]) + (p[2] + p[3]);
        s += __shfl_xor(s, 1, 64);
        s += __shfl_xor(s, 2, 64);
        s += __shfl_xor(s, 4, 64);
        s += __shfl_xor(s, 8, 64);
        s += __shfl_xor(s, 16, 64);
        if (il == 0) y[(size_t)b * 128 + o] = s;
    }
}

extern "C" void kernel_launch(void* const* d_in, const int* in_sizes, int n_in,
                              void* d_out, int out_size, void* d_ws, size_t ws_size,
                              hipStream_t stream) {
    const float* x       = (const float*)d_in[0];   // (batch, 128)
    const float* affine  = (const float*)d_in[1];   // (128, 128, 4)
    const float* mask    = (const float*)d_in[2];   // (128, 128)
    const int*   fun_ids = (const int*)d_in[3];     // (128, 128)

    const int batch = in_sizes[0] / 128;            // 4096

    float* xred     = (float*)d_ws;                 // batch*128 floats (2 MB)
    float* y        = (float*)d_out;                // batch*128
    float* postacts = y + (size_t)batch * 128;      // batch*128*128

    xred_kernel<<<dim3(batch / XR_BB), dim3(256), 0, stream>>>(x, mask, xred);

    kan_main<<<dim3(128 / OGROUP, batch / BCHUNK), dim3(256), 0, stream>>>(
        (const float4*)xred, (const float4*)affine, fun_ids, y, (float4*)postacts);
}